// Round 12
// baseline (519.558 us; speedup 1.0000x reference)
//
#include <hip/hip_runtime.h>
#include <hip/hip_bf16.h>
#include <cstddef>

#define BB   2
#define CTX  1536
#define QQ   512
#define S_LEN 2048
#define DD   256
#define NH   8
#define DH   32
#define DFF  1024
#define NL   6
#define LIN  20
#define HOUTD 10
#define KQ   (CTX / 4)       // 384 keys per wave-group

typedef _Float16 f16x2 __attribute__((ext_vector_type(2)));
typedef _Float16 f16x4 __attribute__((ext_vector_type(4)));
typedef _Float16 f16x8 __attribute__((ext_vector_type(8)));
typedef float f32x4 __attribute__((ext_vector_type(4)));

#define N4_QKV (NL * 3 * DD * DD / 4)
#define N4_WO  (NL * DD * DD / 4)
#define N4_W1  (NL * DFF * DD / 4)
#define N4_W2  (NL * DD * DFF / 4)

// ---------------- fp32 -> f16 convert (all weights, one launch) ----------------
__global__ __launch_bounds__(256) void cvtall_k(
    const float* __restrict__ wqkv, const float* __restrict__ wo,
    const float* __restrict__ w1, const float* __restrict__ w2,
    _Float16* __restrict__ hqkv, _Float16* __restrict__ ho,
    _Float16* __restrict__ h1, _Float16* __restrict__ h2)
{
    int i = blockIdx.x * 256 + threadIdx.x;
    const float* s; _Float16* t; int j = i;
    if (j < N4_QKV) { s = wqkv; t = hqkv; }
    else if ((j -= N4_QKV) < N4_WO) { s = wo; t = ho; }
    else if ((j -= N4_WO) < N4_W1) { s = w1; t = h1; }
    else if ((j -= N4_W1) < N4_W2) { s = w2; t = h2; }
    else return;
    float4 v = ((const float4*)s)[j];
    f16x4 h = {(_Float16)v.x, (_Float16)v.y, (_Float16)v.z, (_Float16)v.w};
    ((f16x4*)t)[j] = h;
}

// ---------------- Embed: Z[b*S+s][d] (+f16 copy, +t_all float) ----------------
__global__ __launch_bounds__(256) void embed_k(
    const float* __restrict__ ctx_x, const float* __restrict__ ctx_z,
    const float* __restrict__ qry_x,
    const float* __restrict__ W_ctx, const float* __restrict__ b_ctx,
    const float* __restrict__ W_qry, const float* __restrict__ b_qry,
    const int* __restrict__ t_ctx, const int* __restrict__ t_qry,
    float* __restrict__ Z, _Float16* __restrict__ Zh, float* __restrict__ tf)
{
    int row = blockIdx.x;            // 0..4095
    int d = threadIdx.x;             // 0..255
    int b = row >> 11, s = row & (S_LEN - 1);
    float acc;
    if (s < CTX) {
        const float* x1 = ctx_x + (size_t)(b * CTX + s) * LIN;
        const float* x2 = ctx_z + (size_t)(b * CTX + s) * HOUTD;
        const float* w = W_ctx + (size_t)d * (LIN + HOUTD);
        acc = b_ctx[d];
        #pragma unroll
        for (int i = 0; i < LIN; i++) acc += x1[i] * w[i];
        #pragma unroll
        for (int i = 0; i < HOUTD; i++) acc += x2[i] * w[LIN + i];
        if (d == 0) tf[row] = (float)t_ctx[b * CTX + s];
    } else {
        int qi = s - CTX;
        const float* x1 = qry_x + (size_t)(b * QQ + qi) * LIN;
        const float* w = W_qry + (size_t)d * (LIN + HOUTD);
        acc = b_qry[d];
        #pragma unroll
        for (int i = 0; i < LIN; i++) acc += x1[i] * w[i];
        if (d == 0) tf[row] = (float)t_qry[b * QQ + qi];
    }
    Z[(size_t)row * DD + d] = acc;
    Zh[(size_t)row * DD + d] = (_Float16)acc;
}

// ---------------- MFMA f16 GEMM (dbuf LDS, pad-40, 1 barrier/step) ----------------
// mode 0: fp32 out Y   mode 1: relu -> f16 Yh   mode 2: f16 Q,K:[B,NH,S,DH] V:[B,NH,DH,S]
__global__ __launch_bounds__(256) void hgemm_k(
    const _Float16* __restrict__ X, const _Float16* __restrict__ W,
    const float* __restrict__ bias, float* __restrict__ Y,
    _Float16* __restrict__ Yh, int M, int N, int K, int mode,
    _Float16* __restrict__ Qh, _Float16* __restrict__ Kh, _Float16* __restrict__ Vh)
{
    __shared__ _Float16 Ah[2][64][40];
    __shared__ _Float16 Bh[2][64][40];
    const int tid = threadIdx.x;
    const int bm = blockIdx.x << 6, bn = blockIdx.y << 6;
    const int lr = tid >> 2;
    const int lk = (tid & 3) << 3;
    const int w = tid >> 6, lane = tid & 63;
    const int c = lane & 15, g = lane >> 4;
    const int wm = (w >> 1) << 5, wn = (w & 1) << 5;

    f32x4 acc00 = {0.f,0.f,0.f,0.f}, acc01 = {0.f,0.f,0.f,0.f};
    f32x4 acc10 = {0.f,0.f,0.f,0.f}, acc11 = {0.f,0.f,0.f,0.f};

    const _Float16* Xp = X + (size_t)(bm + lr) * K + lk;
    const _Float16* Wp = W + (size_t)(bn + lr) * K + lk;

    f16x8 xa = *(const f16x8*)Xp;
    f16x8 wb = *(const f16x8*)Wp;
    const int nt = K >> 5;
    int buf = 0;
    for (int t = 0; t < nt; t++) {
        *(f16x8*)&Ah[buf][lr][lk] = xa;
        *(f16x8*)&Bh[buf][lr][lk] = wb;
        __syncthreads();
        if (t + 1 < nt) {
            xa = *(const f16x8*)(Xp + ((size_t)(t + 1) << 5));
            wb = *(const f16x8*)(Wp + ((size_t)(t + 1) << 5));
        }
        f16x8 a0 = *(const f16x8*)&Ah[buf][wm + c][g << 3];
        f16x8 a1 = *(const f16x8*)&Ah[buf][wm + 16 + c][g << 3];
        f16x8 b0 = *(const f16x8*)&Bh[buf][wn + c][g << 3];
        f16x8 b1 = *(const f16x8*)&Bh[buf][wn + 16 + c][g << 3];
        acc00 = __builtin_amdgcn_mfma_f32_16x16x32_f16(a0, b0, acc00, 0, 0, 0);
        acc01 = __builtin_amdgcn_mfma_f32_16x16x32_f16(a0, b1, acc01, 0, 0, 0);
        acc10 = __builtin_amdgcn_mfma_f32_16x16x32_f16(a1, b0, acc10, 0, 0, 0);
        acc11 = __builtin_amdgcn_mfma_f32_16x16x32_f16(a1, b1, acc11, 0, 0, 0);
        buf ^= 1;
    }

    f32x4 accs[2][2] = {{acc00, acc01}, {acc10, acc11}};
    #pragma unroll
    for (int fm = 0; fm < 2; fm++) {
        #pragma unroll
        for (int fn = 0; fn < 2; fn++) {
            int colb = bn + wn + (fn << 4) + c;
            float bv = bias[colb];
            #pragma unroll
            for (int r = 0; r < 4; r++) {
                int row = bm + wm + (fm << 4) + (g << 2) + r;
                float v = accs[fm][fn][r] + bv;
                if (mode == 0) {
                    Y[(size_t)row * N + colb] = v;
                } else if (mode == 1) {
                    Yh[(size_t)row * N + colb] = (_Float16)fmaxf(v, 0.0f);
                } else {
                    int which = colb >> 8, h = (colb >> 5) & 7, d = colb & 31;
                    int bb2 = row >> 11, ss = row & (S_LEN - 1);
                    int bhi = (bb2 << 3) + h;
                    _Float16 hv = (_Float16)v;
                    if (which == 0)      Qh[((size_t)bhi * S_LEN + ss) * DH + d] = hv;
                    else if (which == 1) Kh[((size_t)bhi * S_LEN + ss) * DH + d] = hv;
                    else                 Vh[((size_t)bhi * DH + d) * S_LEN + ss] = hv;
                }
            }
        }
    }
}

// ---------------- fused Wo GEMM + residual + LayerNorm (BM=16, grid 256) ----------------
__global__ __launch_bounds__(256) void gemmln_k(
    const _Float16* __restrict__ X, const _Float16* __restrict__ W,
    const float* __restrict__ bias, float* __restrict__ Z,
    _Float16* __restrict__ Zh, const float* __restrict__ sw,
    const float* __restrict__ bw)
{
    __shared__ _Float16 Ast[2][16][40];
    __shared__ _Float16 Bst[2][256][40];
    __shared__ float lred[4][16][2];
    const int tid = threadIdx.x;
    const int bm = blockIdx.x << 4;
    const int w = tid >> 6, lane = tid & 63;
    const int c = lane & 15, g = lane >> 4;
    const int br = tid >> 2, bk = (tid & 3) << 3;

    f32x4 acc[4] = {};
    const _Float16* Wp = W + (size_t)br * DD + bk;
    f16x8 p0 = *(const f16x8*)Wp;
    f16x8 p1 = *(const f16x8*)(Wp + (size_t)64 * DD);
    f16x8 p2 = *(const f16x8*)(Wp + (size_t)128 * DD);
    f16x8 p3 = *(const f16x8*)(Wp + (size_t)192 * DD);
    f16x8 xa;
    if (tid < 64) xa = *(const f16x8*)(X + (size_t)(bm + br) * DD + bk);
    int buf = 0;
    #pragma unroll
    for (int t = 0; t < 8; t++) {
        if (tid < 64) *(f16x8*)&Ast[buf][br][bk] = xa;
        *(f16x8*)&Bst[buf][br][bk] = p0;
        *(f16x8*)&Bst[buf][br + 64][bk] = p1;
        *(f16x8*)&Bst[buf][br + 128][bk] = p2;
        *(f16x8*)&Bst[buf][br + 192][bk] = p3;
        __syncthreads();
        if (t < 7) {
            int o = (t + 1) << 5;
            if (tid < 64) xa = *(const f16x8*)(X + (size_t)(bm + br) * DD + o + bk);
            p0 = *(const f16x8*)(Wp + o);
            p1 = *(const f16x8*)(Wp + (size_t)64 * DD + o);
            p2 = *(const f16x8*)(Wp + (size_t)128 * DD + o);
            p3 = *(const f16x8*)(Wp + (size_t)192 * DD + o);
        }
        f16x8 a = *(const f16x8*)&Ast[buf][c][g << 3];
        #pragma unroll
        for (int f = 0; f < 4; f++) {
            f16x8 bfr = *(const f16x8*)&Bst[buf][(w << 6) + (f << 4) + c][g << 3];
            acc[f] = __builtin_amdgcn_mfma_f32_16x16x32_f16(a, bfr, acc[f], 0, 0, 0);
        }
        buf ^= 1;
    }

    float vals[4][4];
    float s1[4] = {0.f,0.f,0.f,0.f}, s2[4] = {0.f,0.f,0.f,0.f};
    #pragma unroll
    for (int f = 0; f < 4; f++) {
        int col = (w << 6) + (f << 4) + c;
        float bv = bias[col];
        #pragma unroll
        for (int r = 0; r < 4; r++) {
            int row = bm + (g << 2) + r;
            float v = acc[f][r] + bv + Z[(size_t)row * DD + col];
            vals[f][r] = v; s1[r] += v; s2[r] += v * v;
        }
    }
    #pragma unroll
    for (int off = 1; off < 16; off <<= 1) {
        #pragma unroll
        for (int r = 0; r < 4; r++) {
            s1[r] += __shfl_xor(s1[r], off, 64);
            s2[r] += __shfl_xor(s2[r], off, 64);
        }
    }
    if (c == 0) {
        #pragma unroll
        for (int r = 0; r < 4; r++) {
            lred[w][(g << 2) + r][0] = s1[r];
            lred[w][(g << 2) + r][1] = s2[r];
        }
    }
    __syncthreads();
    float mu_r[4], rs_r[4];
    #pragma unroll
    for (int r = 0; r < 4; r++) {
        int lr_ = (g << 2) + r;
        float S1 = lred[0][lr_][0] + lred[1][lr_][0] + lred[2][lr_][0] + lred[3][lr_][0];
        float S2 = lred[0][lr_][1] + lred[1][lr_][1] + lred[2][lr_][1] + lred[3][lr_][1];
        float mu = S1 * (1.0f / 256.0f);
        float var = S2 * (1.0f / 256.0f) - mu * mu;
        mu_r[r] = mu; rs_r[r] = rsqrtf(var + 1e-5f);
    }
    #pragma unroll
    for (int f = 0; f < 4; f++) {
        int col = (w << 6) + (f << 4) + c;
        float swv = sw[col], bwv = bw[col];
        #pragma unroll
        for (int r = 0; r < 4; r++) {
            int row = bm + (g << 2) + r;
            float o = (vals[f][r] - mu_r[r]) * rs_r[r] * swv + bwv;
            Z[(size_t)row * DD + col] = o;
            Zh[(size_t)row * DD + col] = (_Float16)o;
        }
    }
}

// ---------------- Residual + LN, one WAVE per row (no LDS, no barrier) ----------------
__global__ __launch_bounds__(256) void ln4_k(
    float* __restrict__ Z, const float* __restrict__ Y,
    const float* __restrict__ sw, const float* __restrict__ bw,
    _Float16* __restrict__ Zh)
{
    const int w = threadIdx.x >> 6, lane = threadIdx.x & 63;
    const int row = (blockIdx.x << 2) + w;
    float4 z = ((const float4*)(Z + (size_t)row * DD))[lane];
    float4 y = ((const float4*)(Y + (size_t)row * DD))[lane];
    float x0 = z.x + y.x, x1 = z.y + y.y, x2 = z.z + y.z, x3 = z.w + y.w;
    float s1 = (x0 + x1) + (x2 + x3);
    float s2 = (x0 * x0 + x1 * x1) + (x2 * x2 + x3 * x3);
    #pragma unroll
    for (int off = 1; off < 64; off <<= 1) {
        s1 += __shfl_xor(s1, off, 64);
        s2 += __shfl_xor(s2, off, 64);
    }
    float mu = s1 * (1.0f / 256.0f);
    float var = s2 * (1.0f / 256.0f) - mu * mu;
    float rs = rsqrtf(var + 1e-5f);
    float4 sv = ((const float4*)sw)[lane];
    float4 bv = ((const float4*)bw)[lane];
    float o0 = (x0 - mu) * rs * sv.x + bv.x;
    float o1 = (x1 - mu) * rs * sv.y + bv.y;
    float o2 = (x2 - mu) * rs * sv.z + bv.z;
    float o3 = (x3 - mu) * rs * sv.w + bv.w;
    ((float4*)(Z + (size_t)row * DD))[lane] = make_float4(o0, o1, o2, o3);
    f16x4 oh = {(_Float16)o0, (_Float16)o1, (_Float16)o2, (_Float16)o3};
    ((f16x4*)(Zh + (size_t)row * DD))[lane] = oh;
}

// ---------------- MFMA flash attention ----------------
// 1024 thr = 16 waves = 4 key-split groups x 4 query tiles. Grid 512 ->
// 2 blocks/CU x 16 waves = 32 waves/CU (max). Each wg stages its K/V
// 64-key tiles (dbuf); merge scratch ALIASES K/V LDS after a barrier.
__global__ __launch_bounds__(1024, 8) void attn_k(
    const _Float16* __restrict__ Qf, const _Float16* __restrict__ Kf,
    const _Float16* __restrict__ Vf, const float* __restrict__ tf_all,
    const float* __restrict__ alpha, _Float16* __restrict__ O)
{
    const int bh = blockIdx.x >> 5;           // /(S/64)=32
    const int itile = blockIdx.x & 31;
    const int b = bh >> 3, h = bh & 7;
    const int tid = threadIdx.x;
    const int w16 = tid >> 6;                 // 0..15
    const int wg = w16 >> 2;                  // key-split 0..3
    const int wq = w16 & 3;                   // query tile 0..3
    const int ltid = tid & 255;               // within wave-group
    const int lane = tid & 63;
    const int c = lane & 15, g = lane >> 4;
    const int i0 = (itile << 6) + (wq << 4);
    const int jbase = wg * KQ;

    __shared__ _Float16 Klds[4][2][64][40];   // 40960 B
    __shared__ _Float16 Vlds[4][2][32][72];   // 36864 B
    // merge-phase aliases (valid only after the post-loop barrier):
    float (*sacc)[16][36] = (float (*)[16][36]) & Klds[0][0][0][0]; // [16][16][36]
    float (*sml)[2][16] = (float (*)[2][16]) & Vlds[0][0][0][0];    // [16][2][16]

    const float LOG2E = 1.44269504088896f;
    const float sc2 = 0.17677669529663687f * LOG2E;
    const float ah2 = alpha[h] * LOG2E;

    const _Float16* Qbh = Qf + (size_t)bh * S_LEN * DH;
    const _Float16* Kbh = Kf + (size_t)bh * S_LEN * DH;
    const _Float16* Vbh = Vf + (size_t)bh * DH * S_LEN;
    const float* tb = tf_all + b * S_LEN;

    f16x8 qfrag = *(const f16x8*)(Qbh + (size_t)(i0 + c) * DH + (g << 3));
    const float ti = tb[i0 + c];

    const int kr = ltid >> 2, kc = (ltid & 3) << 3;
    const int vr = ltid >> 3, vc = (ltid & 7) << 3;

    float m2 = -3.0e38f, l = 0.0f;
    f32x4 acc0 = {0.f, 0.f, 0.f, 0.f};
    f32x4 acc1 = {0.f, 0.f, 0.f, 0.f};
    const f32x4 zero = {0.f, 0.f, 0.f, 0.f};

    f16x8 kpre = *(const f16x8*)(Kbh + (size_t)(jbase + kr) * DH + kc);
    f16x8 vpre = *(const f16x8*)(Vbh + (size_t)vr * S_LEN + jbase + vc);
    int buf = 0;

    for (int kt = 0; kt < KQ; kt += 64) {
        *(f16x8*)&Klds[wg][buf][kr][kc] = kpre;
        *(f16x8*)&Vlds[wg][buf][vr][vc] = vpre;
        __syncthreads();
        if (kt + 64 < KQ) {
            kpre = *(const f16x8*)(Kbh + (size_t)(jbase + kt + 64 + kr) * DH + kc);
            vpre = *(const f16x8*)(Vbh + (size_t)vr * S_LEN + jbase + kt + 64 + vc);
        }
        #pragma unroll
        for (int jj = 0; jj < 64; jj += 32) {
            const int j0 = jbase + kt + jj;
            f16x8 kf0 = *(const f16x8*)&Klds[wg][buf][jj + c][g << 3];
            f16x8 kf1 = *(const f16x8*)&Klds[wg][buf][jj + 16 + c][g << 3];
            f32x4 dA = __builtin_amdgcn_mfma_f32_16x16x32_f16(kf0, qfrag, zero, 0, 0, 0);
            f32x4 dB = __builtin_amdgcn_mfma_f32_16x16x32_f16(kf1, qfrag, zero, 0, 0, 0);
            float4 tjA = *(const float4*)(tb + j0 + (g << 2));
            float4 tjB = *(const float4*)(tb + j0 + 16 + (g << 2));
            float eA0 = ti - tjA.x, eA1 = ti - tjA.y, eA2 = ti - tjA.z, eA3 = ti - tjA.w;
            float eB0 = ti - tjB.x, eB1 = ti - tjB.y, eB2 = ti - tjB.z, eB3 = ti - tjB.w;
            float sA0 = (eA0 >= 0.f) ? dA[0] * sc2 - ah2 * eA0 : -1e9f;
            float sA1 = (eA1 >= 0.f) ? dA[1] * sc2 - ah2 * eA1 : -1e9f;
            float sA2 = (eA2 >= 0.f) ? dA[2] * sc2 - ah2 * eA2 : -1e9f;
            float sA3 = (eA3 >= 0.f) ? dA[3] * sc2 - ah2 * eA3 : -1e9f;
            float sB0 = (eB0 >= 0.f) ? dB[0] * sc2 - ah2 * eB0 : -1e9f;
            float sB1 = (eB1 >= 0.f) ? dB[1] * sc2 - ah2 * eB1 : -1e9f;
            float sB2 = (eB2 >= 0.f) ? dB[2] * sc2 - ah2 * eB2 : -1e9f;
            float sB3 = (eB3 >= 0.f) ? dB[3] * sc2 - ah2 * eB3 : -1e9f;
            float pmaxl = fmaxf(fmaxf(fmaxf(sA0, sA1), fmaxf(sA2, sA3)),
                                fmaxf(fmaxf(sB0, sB1), fmaxf(sB2, sB3)));
            if (__any(pmaxl > m2 + 8.0f)) {
                float pm = fmaxf(pmaxl, __shfl_xor(pmaxl, 16, 64));
                pm = fmaxf(pm, __shfl_xor(pm, 32, 64));
                float mnew = fmaxf(m2, pm);
                float fsc = __builtin_amdgcn_exp2f(m2 - mnew);
                m2 = mnew;
                l *= fsc; acc0 *= fsc; acc1 *= fsc;
            }
            float pA0 = __builtin_amdgcn_exp2f(sA0 - m2);
            float pA1 = __builtin_amdgcn_exp2f(sA1 - m2);
            float pA2 = __builtin_amdgcn_exp2f(sA2 - m2);
            float pA3 = __builtin_amdgcn_exp2f(sA3 - m2);
            float pB0 = __builtin_amdgcn_exp2f(sB0 - m2);
            float pB1 = __builtin_amdgcn_exp2f(sB1 - m2);
            float pB2 = __builtin_amdgcn_exp2f(sB2 - m2);
            float pB3 = __builtin_amdgcn_exp2f(sB3 - m2);
            l += ((pA0 + pA1) + (pA2 + pA3)) + ((pB0 + pB1) + (pB2 + pB3));
            f16x4 pfA = {(_Float16)pA0, (_Float16)pA1, (_Float16)pA2, (_Float16)pA3};
            f16x4 pfB = {(_Float16)pB0, (_Float16)pB1, (_Float16)pB2, (_Float16)pB3};
            f16x4 vA0 = *(const f16x4*)&Vlds[wg][buf][c][jj + (g << 2)];
            f16x4 vA1 = *(const f16x4*)&Vlds[wg][buf][16 + c][jj + (g << 2)];
            f16x4 vB0 = *(const f16x4*)&Vlds[wg][buf][c][jj + 16 + (g << 2)];
            f16x4 vB1 = *(const f16x4*)&Vlds[wg][buf][16 + c][jj + 16 + (g << 2)];
            acc0 = __builtin_amdgcn_mfma_f32_16x16x16f16(vA0, pfA, acc0, 0, 0, 0);
            acc0 = __builtin_amdgcn_mfma_f32_16x16x16f16(vB0, pfB, acc0, 0, 0, 0);
            acc1 = __builtin_amdgcn_mfma_f32_16x16x16f16(vA1, pfA, acc1, 0, 0, 0);
            acc1 = __builtin_amdgcn_mfma_f32_16x16x16f16(vB1, pfB, acc1, 0, 0, 0);
        }
        buf ^= 1;
    }

    // reduce the per-lane l across the 4 g-groups
    l += __shfl_xor(l, 16, 64);
    l += __shfl_xor(l, 32, 64);

    // all waves done with K/V LDS -> safe to alias as merge scratch
    __syncthreads();
    *(f32x4*)&sacc[w16][c][g << 2] = acc0;
    *(f32x4*)&sacc[w16][c][16 + (g << 2)] = acc1;
    if (g == 0) { sml[w16][0][c] = m2; sml[w16][1][c] = l; }
    __syncthreads();

    // 4-way merge: thread t -> qtile qt, query q, dh pair dh0
    {
        const int qt = tid >> 8;              // 0..3
        const int q = (tid >> 4) & 15;        // 0..15
        const int dh0 = (tid & 15) << 1;      // 0,2,..,30
        const int i4 = qt;                    // partials at w16 = sp*4 + qt
        float m0 = sml[i4][0][q], m1 = sml[i4 + 4][0][q];
        float m2_ = sml[i4 + 8][0][q], m3 = sml[i4 + 12][0][q];
        float M = fmaxf(fmaxf(m0, m1), fmaxf(m2_, m3));
        float f0 = __builtin_amdgcn_exp2f(m0 - M);
        float f1 = __builtin_amdgcn_exp2f(m1 - M);
        float f2 = __builtin_amdgcn_exp2f(m2_ - M);
        float f3 = __builtin_amdgcn_exp2f(m3 - M);
        float L = sml[i4][1][q] * f0 + sml[i4 + 4][1][q] * f1
                + sml[i4 + 8][1][q] * f2 + sml[i4 + 12][1][q] * f3;
        float a0 = sacc[i4][q][dh0] * f0 + sacc[i4 + 4][q][dh0] * f1
                 + sacc[i4 + 8][q][dh0] * f2 + sacc[i4 + 12][q][dh0] * f3;
        float a1 = sacc[i4][q][dh0 + 1] * f0 + sacc[i4 + 4][q][dh0 + 1] * f1
                 + sacc[i4 + 8][q][dh0 + 1] * f2 + sacc[i4 + 12][q][dh0 + 1] * f3;
        if (M < -4.9e8f) {
            // fully-masked row: reference = uniform softmax over ALL 2048 keys;
            // ctx part already uniform in a0/a1 (p=1 per key); add query keys.
            const _Float16* v0p = Vbh + (size_t)dh0 * S_LEN + CTX;
            const _Float16* v1p = v0p + S_LEN;
            float vs0 = 0.f, vs1 = 0.f;
            for (int j = 0; j < QQ; j += 8) {
                f16x8 x0 = *(const f16x8*)(v0p + j);
                f16x8 x1 = *(const f16x8*)(v1p + j);
                #pragma unroll
                for (int e = 0; e < 8; e++) { vs0 += (float)x0[e]; vs1 += (float)x1[e]; }
            }
            a0 += vs0; a1 += vs1; L += (float)QQ;
        }
        float inv = 1.0f / L;
        int row = b * S_LEN + (itile << 6) + (qt << 4) + q;
        f16x2 o = {(_Float16)(a0 * inv), (_Float16)(a1 * inv)};
        *(f16x2*)(O + (size_t)row * DD + h * DH + dh0) = o;
    }
}

// ---------------- Output head ----------------
__global__ __launch_bounds__(256) void outhead_k(
    const float* __restrict__ Z, const float* __restrict__ Wout,
    const float* __restrict__ bout, float* __restrict__ out)
{
    int tid = threadIdx.x;
    int rloc = tid >> 4, ho = tid & 15;
    int qrow = blockIdx.x * 16 + rloc;
    int b = qrow >> 9, qi = qrow & (QQ - 1);
    if (ho < HOUTD) {
        const float* z = Z + (size_t)(b * S_LEN + CTX + qi) * DD;
        const float* wr = Wout + (size_t)ho * DD;
        float s = 0.0f;
        for (int d = 0; d < DD; d += 4) {
            float4 zv = *(const float4*)(z + d);
            float4 wv = *(const float4*)(wr + d);
            s += zv.x * wv.x + zv.y * wv.y + zv.z * wv.z + zv.w * wv.w;
        }
        out[(size_t)(b * QQ + qi) * HOUTD + ho] = s + bout[ho];
    }
}

extern "C" void kernel_launch(void* const* d_in, const int* in_sizes, int n_in,
                              void* d_out, int out_size, void* d_ws, size_t ws_size,
                              hipStream_t stream) {
    (void)in_sizes; (void)n_in; (void)out_size; (void)ws_size;
    const float* ctx_x = (const float*)d_in[0];
    const float* ctx_z = (const float*)d_in[1];
    const float* qry_x = (const float*)d_in[2];
    const int* t_ctx = (const int*)d_in[3];
    const int* t_qry = (const int*)d_in[4];
    const float* W_ctx = (const float*)d_in[5];
    const float* b_ctx = (const float*)d_in[6];
    const float* W_qry = (const float*)d_in[7];
    const float* b_qry = (const float*)d_in[8];
    const float* alpha = (const float*)d_in[9];
    const float* Wqkv = (const float*)d_in[10];
    const float* bqkv = (const float*)d_in[11];
    const float* Wo = (const float*)d_in[12];
    const float* bo = (const float*)d_in[13];
    const float* ln1_s = (const float*)d_in[14];
    const float* ln1_b = (const float*)d_in[15];
    const float* W1 = (const float*)d_in[16];
    const float* b1 = (const float*)d_in[17];
    const float* W2 = (const float*)d_in[18];
    const float* b2 = (const float*)d_in[19];
    const float* ln2_s = (const float*)d_in[20];
    const float* ln2_b = (const float*)d_in[21];
    const float* W_out = (const float*)d_in[22];
    const float* b_out = (const float*)d_in[23];

    float* ws = (float*)d_ws;
    const size_t MTOT = (size_t)BB * S_LEN;       // 4096
    const size_t ZSZ = MTOT * DD;                 // 1M floats
    float* Z   = ws;                              // [0, 1M) f32
    float* Yb  = ws + ZSZ;                        // [1M, 2M) f32
    _Float16* Zh   = (_Float16*)(ws + 2 * ZSZ);          // 1M halfs
    _Float16* AYh  = (_Float16*)(ws + 2 * ZSZ + ZSZ / 2);
    _Float16* FF1h = (_Float16*)(ws + 3 * ZSZ);          // 4M halfs -> [3M,5M)
    _Float16* Qh   = (_Float16*)(ws + 5 * ZSZ);
    _Float16* Kh   = (_Float16*)(ws + 5 * ZSZ + ZSZ / 2);
    _Float16* Vh   = (_Float16*)(ws + 6 * ZSZ);
    float* tf_all  = ws + 6 * ZSZ + ZSZ / 2;             // 4096 floats
    _Float16* Whqkv = (_Float16*)(ws + 6 * ZSZ + ZSZ / 2 + 4096);
    _Float16* Who   = Whqkv + (size_t)NL * 3 * DD * DD;
    _Float16* Wh1   = Who   + (size_t)NL * DD * DD;
    _Float16* Wh2   = Wh1   + (size_t)NL * DFF * DD;

    {
        int n4tot = N4_QKV + N4_WO + N4_W1 + N4_W2;
        cvtall_k<<<(n4tot + 255) / 256, 256, 0, stream>>>(
            Wqkv, Wo, W1, W2, Whqkv, Who, Wh1, Wh2);
    }

    embed_k<<<MTOT, 256, 0, stream>>>(ctx_x, ctx_z, qry_x, W_ctx, b_ctx, W_qry, b_qry,
                                      t_ctx, t_qry, Z, Zh, tf_all);

    for (int l = 0; l < NL; l++) {
        hgemm_k<<<dim3(MTOT / 64, (3 * DD) / 64), 256, 0, stream>>>(
            Zh, Whqkv + (size_t)l * 3 * DD * DD, bqkv + (size_t)l * 3 * DD,
            nullptr, nullptr, (int)MTOT, 3 * DD, DD, 2, Qh, Kh, Vh);
        attn_k<<<BB * NH * (S_LEN / 64), 1024, 0, stream>>>(
            Qh, Kh, Vh, tf_all, alpha, AYh);
        gemmln_k<<<MTOT / 16, 256, 0, stream>>>(
            AYh, Who + (size_t)l * DD * DD, bo + (size_t)l * DD,
            Z, Zh, ln1_s + (size_t)l * DD, ln1_b + (size_t)l * DD);
        hgemm_k<<<dim3(MTOT / 64, DFF / 64), 256, 0, stream>>>(
            Zh, Wh1 + (size_t)l * DFF * DD, b1 + (size_t)l * DFF,
            nullptr, FF1h, (int)MTOT, DFF, DD, 1, nullptr, nullptr, nullptr);
        hgemm_k<<<dim3(MTOT / 64, DD / 64), 256, 0, stream>>>(
            FF1h, Wh2 + (size_t)l * DD * DFF, b2 + (size_t)l * DD,
            Yb, nullptr, (int)MTOT, DD, DFF, 0, nullptr, nullptr, nullptr);
        ln4_k<<<MTOT / 4, 256, 0, stream>>>(
            Z, Yb, ln2_s + (size_t)l * DD, ln2_b + (size_t)l * DD, Zh);
    }

    outhead_k<<<(BB * QQ) / 16, 256, 0, stream>>>(Z, W_out, b_out, (float*)d_out);
}

// Round 13
// 472.627 us; speedup vs baseline: 1.0993x; 1.0993x over previous
//
#include <hip/hip_runtime.h>
#include <hip/hip_bf16.h>
#include <cstddef>

#define BB   2
#define CTX  1536
#define QQ   512
#define S_LEN 2048
#define DD   256
#define NH   8
#define DH   32
#define DFF  1024
#define NL   6
#define LIN  20
#define HOUTD 10
#define KHALF (CTX / 2)      // 768 keys per wave-group

typedef _Float16 f16x2 __attribute__((ext_vector_type(2)));
typedef _Float16 f16x4 __attribute__((ext_vector_type(4)));
typedef _Float16 f16x8 __attribute__((ext_vector_type(8)));
typedef float f32x4 __attribute__((ext_vector_type(4)));

#define N4_QKV (NL * 3 * DD * DD / 4)
#define N4_WO  (NL * DD * DD / 4)
#define N4_W1  (NL * DFF * DD / 4)
#define N4_W2  (NL * DD * DFF / 4)

// ---------------- fp32 -> f16 convert (all weights, one launch) ----------------
__global__ __launch_bounds__(256) void cvtall_k(
    const float* __restrict__ wqkv, const float* __restrict__ wo,
    const float* __restrict__ w1, const float* __restrict__ w2,
    _Float16* __restrict__ hqkv, _Float16* __restrict__ ho,
    _Float16* __restrict__ h1, _Float16* __restrict__ h2)
{
    int i = blockIdx.x * 256 + threadIdx.x;
    const float* s; _Float16* t; int j = i;
    if (j < N4_QKV) { s = wqkv; t = hqkv; }
    else if ((j -= N4_QKV) < N4_WO) { s = wo; t = ho; }
    else if ((j -= N4_WO) < N4_W1) { s = w1; t = h1; }
    else if ((j -= N4_W1) < N4_W2) { s = w2; t = h2; }
    else return;
    float4 v = ((const float4*)s)[j];
    f16x4 h = {(_Float16)v.x, (_Float16)v.y, (_Float16)v.z, (_Float16)v.w};
    ((f16x4*)t)[j] = h;
}

// ---------------- Embed: Z[b*S+s][d] (+f16 copy, +t_all float) ----------------
__global__ __launch_bounds__(256) void embed_k(
    const float* __restrict__ ctx_x, const float* __restrict__ ctx_z,
    const float* __restrict__ qry_x,
    const float* __restrict__ W_ctx, const float* __restrict__ b_ctx,
    const float* __restrict__ W_qry, const float* __restrict__ b_qry,
    const int* __restrict__ t_ctx, const int* __restrict__ t_qry,
    float* __restrict__ Z, _Float16* __restrict__ Zh, float* __restrict__ tf)
{
    int row = blockIdx.x;            // 0..4095
    int d = threadIdx.x;             // 0..255
    int b = row >> 11, s = row & (S_LEN - 1);
    float acc;
    if (s < CTX) {
        const float* x1 = ctx_x + (size_t)(b * CTX + s) * LIN;
        const float* x2 = ctx_z + (size_t)(b * CTX + s) * HOUTD;
        const float* w = W_ctx + (size_t)d * (LIN + HOUTD);
        acc = b_ctx[d];
        #pragma unroll
        for (int i = 0; i < LIN; i++) acc += x1[i] * w[i];
        #pragma unroll
        for (int i = 0; i < HOUTD; i++) acc += x2[i] * w[LIN + i];
        if (d == 0) tf[row] = (float)t_ctx[b * CTX + s];
    } else {
        int qi = s - CTX;
        const float* x1 = qry_x + (size_t)(b * QQ + qi) * LIN;
        const float* w = W_qry + (size_t)d * (LIN + HOUTD);
        acc = b_qry[d];
        #pragma unroll
        for (int i = 0; i < LIN; i++) acc += x1[i] * w[i];
        if (d == 0) tf[row] = (float)t_qry[b * QQ + qi];
    }
    Z[(size_t)row * DD + d] = acc;
    Zh[(size_t)row * DD + d] = (_Float16)acc;
}

// ---------------- MFMA f16 GEMM (dbuf LDS, pad-40, 1 barrier/step) ----------------
// mode 0: fp32 out Y   mode 1: relu -> f16 Yh   mode 2: f16 Q,K:[B,NH,S,DH] V:[B,NH,DH,S]
__global__ __launch_bounds__(256) void hgemm_k(
    const _Float16* __restrict__ X, const _Float16* __restrict__ W,
    const float* __restrict__ bias, float* __restrict__ Y,
    _Float16* __restrict__ Yh, int M, int N, int K, int mode,
    _Float16* __restrict__ Qh, _Float16* __restrict__ Kh, _Float16* __restrict__ Vh)
{
    __shared__ _Float16 Ah[2][64][40];
    __shared__ _Float16 Bh[2][64][40];
    const int tid = threadIdx.x;
    const int bm = blockIdx.x << 6, bn = blockIdx.y << 6;
    const int lr = tid >> 2;
    const int lk = (tid & 3) << 3;
    const int w = tid >> 6, lane = tid & 63;
    const int c = lane & 15, g = lane >> 4;
    const int wm = (w >> 1) << 5, wn = (w & 1) << 5;

    f32x4 acc00 = {0.f,0.f,0.f,0.f}, acc01 = {0.f,0.f,0.f,0.f};
    f32x4 acc10 = {0.f,0.f,0.f,0.f}, acc11 = {0.f,0.f,0.f,0.f};

    const _Float16* Xp = X + (size_t)(bm + lr) * K + lk;
    const _Float16* Wp = W + (size_t)(bn + lr) * K + lk;

    f16x8 xa = *(const f16x8*)Xp;
    f16x8 wb = *(const f16x8*)Wp;
    const int nt = K >> 5;
    int buf = 0;
    for (int t = 0; t < nt; t++) {
        *(f16x8*)&Ah[buf][lr][lk] = xa;
        *(f16x8*)&Bh[buf][lr][lk] = wb;
        __syncthreads();
        if (t + 1 < nt) {
            xa = *(const f16x8*)(Xp + ((size_t)(t + 1) << 5));
            wb = *(const f16x8*)(Wp + ((size_t)(t + 1) << 5));
        }
        f16x8 a0 = *(const f16x8*)&Ah[buf][wm + c][g << 3];
        f16x8 a1 = *(const f16x8*)&Ah[buf][wm + 16 + c][g << 3];
        f16x8 b0 = *(const f16x8*)&Bh[buf][wn + c][g << 3];
        f16x8 b1 = *(const f16x8*)&Bh[buf][wn + 16 + c][g << 3];
        acc00 = __builtin_amdgcn_mfma_f32_16x16x32_f16(a0, b0, acc00, 0, 0, 0);
        acc01 = __builtin_amdgcn_mfma_f32_16x16x32_f16(a0, b1, acc01, 0, 0, 0);
        acc10 = __builtin_amdgcn_mfma_f32_16x16x32_f16(a1, b0, acc10, 0, 0, 0);
        acc11 = __builtin_amdgcn_mfma_f32_16x16x32_f16(a1, b1, acc11, 0, 0, 0);
        buf ^= 1;
    }

    f32x4 accs[2][2] = {{acc00, acc01}, {acc10, acc11}};
    #pragma unroll
    for (int fm = 0; fm < 2; fm++) {
        #pragma unroll
        for (int fn = 0; fn < 2; fn++) {
            int colb = bn + wn + (fn << 4) + c;
            float bv = bias[colb];
            #pragma unroll
            for (int r = 0; r < 4; r++) {
                int row = bm + wm + (fm << 4) + (g << 2) + r;
                float v = accs[fm][fn][r] + bv;
                if (mode == 0) {
                    Y[(size_t)row * N + colb] = v;
                } else if (mode == 1) {
                    Yh[(size_t)row * N + colb] = (_Float16)fmaxf(v, 0.0f);
                } else {
                    int which = colb >> 8, h = (colb >> 5) & 7, d = colb & 31;
                    int bb2 = row >> 11, ss = row & (S_LEN - 1);
                    int bhi = (bb2 << 3) + h;
                    _Float16 hv = (_Float16)v;
                    if (which == 0)      Qh[((size_t)bhi * S_LEN + ss) * DH + d] = hv;
                    else if (which == 1) Kh[((size_t)bhi * S_LEN + ss) * DH + d] = hv;
                    else                 Vh[((size_t)bhi * DH + d) * S_LEN + ss] = hv;
                }
            }
        }
    }
}

// ---------------- fused Wo GEMM + residual + LayerNorm (BM=16, grid 256) ----------------
__global__ __launch_bounds__(256) void gemmln_k(
    const _Float16* __restrict__ X, const _Float16* __restrict__ W,
    const float* __restrict__ bias, float* __restrict__ Z,
    _Float16* __restrict__ Zh, const float* __restrict__ sw,
    const float* __restrict__ bw)
{
    __shared__ _Float16 Ast[2][16][40];
    __shared__ _Float16 Bst[2][256][40];
    __shared__ float lred[4][16][2];
    const int tid = threadIdx.x;
    const int bm = blockIdx.x << 4;
    const int w = tid >> 6, lane = tid & 63;
    const int c = lane & 15, g = lane >> 4;
    const int br = tid >> 2, bk = (tid & 3) << 3;

    f32x4 acc[4] = {};
    const _Float16* Wp = W + (size_t)br * DD + bk;
    f16x8 p0 = *(const f16x8*)Wp;
    f16x8 p1 = *(const f16x8*)(Wp + (size_t)64 * DD);
    f16x8 p2 = *(const f16x8*)(Wp + (size_t)128 * DD);
    f16x8 p3 = *(const f16x8*)(Wp + (size_t)192 * DD);
    f16x8 xa;
    if (tid < 64) xa = *(const f16x8*)(X + (size_t)(bm + br) * DD + bk);
    int buf = 0;
    #pragma unroll
    for (int t = 0; t < 8; t++) {
        if (tid < 64) *(f16x8*)&Ast[buf][br][bk] = xa;
        *(f16x8*)&Bst[buf][br][bk] = p0;
        *(f16x8*)&Bst[buf][br + 64][bk] = p1;
        *(f16x8*)&Bst[buf][br + 128][bk] = p2;
        *(f16x8*)&Bst[buf][br + 192][bk] = p3;
        __syncthreads();
        if (t < 7) {
            int o = (t + 1) << 5;
            if (tid < 64) xa = *(const f16x8*)(X + (size_t)(bm + br) * DD + o + bk);
            p0 = *(const f16x8*)(Wp + o);
            p1 = *(const f16x8*)(Wp + (size_t)64 * DD + o);
            p2 = *(const f16x8*)(Wp + (size_t)128 * DD + o);
            p3 = *(const f16x8*)(Wp + (size_t)192 * DD + o);
        }
        f16x8 a = *(const f16x8*)&Ast[buf][c][g << 3];
        #pragma unroll
        for (int f = 0; f < 4; f++) {
            f16x8 bfr = *(const f16x8*)&Bst[buf][(w << 6) + (f << 4) + c][g << 3];
            acc[f] = __builtin_amdgcn_mfma_f32_16x16x32_f16(a, bfr, acc[f], 0, 0, 0);
        }
        buf ^= 1;
    }

    float vals[4][4];
    float s1[4] = {0.f,0.f,0.f,0.f}, s2[4] = {0.f,0.f,0.f,0.f};
    #pragma unroll
    for (int f = 0; f < 4; f++) {
        int col = (w << 6) + (f << 4) + c;
        float bv = bias[col];
        #pragma unroll
        for (int r = 0; r < 4; r++) {
            int row = bm + (g << 2) + r;
            float v = acc[f][r] + bv + Z[(size_t)row * DD + col];
            vals[f][r] = v; s1[r] += v; s2[r] += v * v;
        }
    }
    #pragma unroll
    for (int off = 1; off < 16; off <<= 1) {
        #pragma unroll
        for (int r = 0; r < 4; r++) {
            s1[r] += __shfl_xor(s1[r], off, 64);
            s2[r] += __shfl_xor(s2[r], off, 64);
        }
    }
    if (c == 0) {
        #pragma unroll
        for (int r = 0; r < 4; r++) {
            lred[w][(g << 2) + r][0] = s1[r];
            lred[w][(g << 2) + r][1] = s2[r];
        }
    }
    __syncthreads();
    float mu_r[4], rs_r[4];
    #pragma unroll
    for (int r = 0; r < 4; r++) {
        int lr_ = (g << 2) + r;
        float S1 = lred[0][lr_][0] + lred[1][lr_][0] + lred[2][lr_][0] + lred[3][lr_][0];
        float S2 = lred[0][lr_][1] + lred[1][lr_][1] + lred[2][lr_][1] + lred[3][lr_][1];
        float mu = S1 * (1.0f / 256.0f);
        float var = S2 * (1.0f / 256.0f) - mu * mu;
        mu_r[r] = mu; rs_r[r] = rsqrtf(var + 1e-5f);
    }
    #pragma unroll
    for (int f = 0; f < 4; f++) {
        int col = (w << 6) + (f << 4) + c;
        float swv = sw[col], bwv = bw[col];
        #pragma unroll
        for (int r = 0; r < 4; r++) {
            int row = bm + (g << 2) + r;
            float o = (vals[f][r] - mu_r[r]) * rs_r[r] * swv + bwv;
            Z[(size_t)row * DD + col] = o;
            Zh[(size_t)row * DD + col] = (_Float16)o;
        }
    }
}

// ---------------- Residual + LN, one WAVE per row (no LDS, no barrier) ----------------
__global__ __launch_bounds__(256) void ln4_k(
    float* __restrict__ Z, const float* __restrict__ Y,
    const float* __restrict__ sw, const float* __restrict__ bw,
    _Float16* __restrict__ Zh)
{
    const int w = threadIdx.x >> 6, lane = threadIdx.x & 63;
    const int row = (blockIdx.x << 2) + w;
    float4 z = ((const float4*)(Z + (size_t)row * DD))[lane];
    float4 y = ((const float4*)(Y + (size_t)row * DD))[lane];
    float x0 = z.x + y.x, x1 = z.y + y.y, x2 = z.z + y.z, x3 = z.w + y.w;
    float s1 = (x0 + x1) + (x2 + x3);
    float s2 = (x0 * x0 + x1 * x1) + (x2 * x2 + x3 * x3);
    #pragma unroll
    for (int off = 1; off < 64; off <<= 1) {
        s1 += __shfl_xor(s1, off, 64);
        s2 += __shfl_xor(s2, off, 64);
    }
    float mu = s1 * (1.0f / 256.0f);
    float var = s2 * (1.0f / 256.0f) - mu * mu;
    float rs = rsqrtf(var + 1e-5f);
    float4 sv = ((const float4*)sw)[lane];
    float4 bv = ((const float4*)bw)[lane];
    float o0 = (x0 - mu) * rs * sv.x + bv.x;
    float o1 = (x1 - mu) * rs * sv.y + bv.y;
    float o2 = (x2 - mu) * rs * sv.z + bv.z;
    float o3 = (x3 - mu) * rs * sv.w + bv.w;
    ((float4*)(Z + (size_t)row * DD))[lane] = make_float4(o0, o1, o2, o3);
    f16x4 oh = {(_Float16)o0, (_Float16)o1, (_Float16)o2, (_Float16)o3};
    ((f16x4*)(Zh + (size_t)row * DD))[lane] = oh;
}

// ---------------- MFMA flash attention ----------------
// 512 thr = 8 waves = 2 key-split groups x 4 query tiles. Single-buffered
// LDS (19.5 KB, merge scratch aliased) -> 4 blocks/CU x 8 waves = 32
// waves/CU when VGPR <= 64 (lean body: no prefetch regs).
__global__ __launch_bounds__(512, 8) void attn_k(
    const _Float16* __restrict__ Qf, const _Float16* __restrict__ Kf,
    const _Float16* __restrict__ Vf, const float* __restrict__ tf_all,
    const float* __restrict__ alpha, _Float16* __restrict__ O)
{
    const int bh = blockIdx.x >> 5;           // /(S/64)=32
    const int itile = blockIdx.x & 31;
    const int b = bh >> 3, h = bh & 7;
    const int tid = threadIdx.x;
    const int w8 = tid >> 6;                  // 0..7
    const int wg = w8 >> 2;                   // key-split 0/1
    const int wq = w8 & 3;                    // query tile 0..3
    const int ltid = tid & 255;               // within wave-group
    const int lane = tid & 63;
    const int c = lane & 15, g = lane >> 4;
    const int i0 = (itile << 6) + (wq << 4);
    const int jbase = wg * KHALF;

    // 19456 B total; merge phase aliases the same memory after a barrier.
    __shared__ __align__(16) char smem[19456];
    _Float16 (*Kl)[64][40] = (_Float16(*)[64][40])smem;            // 10240 B
    _Float16 (*Vl)[32][72] = (_Float16(*)[32][72])(smem + 10240);  //  9216 B
    float (*sacc)[16][36] = (float(*)[16][36])smem;                // 18432 B
    float (*sml)[2][16] = (float(*)[2][16])(smem + 18432);         //  1024 B

    const float LOG2E = 1.44269504088896f;
    const float sc2 = 0.17677669529663687f * LOG2E;
    const float ah2 = alpha[h] * LOG2E;

    const _Float16* Qbh = Qf + (size_t)bh * S_LEN * DH;
    const _Float16* Kbh = Kf + (size_t)bh * S_LEN * DH;
    const _Float16* Vbh = Vf + (size_t)bh * DH * S_LEN;
    const float* tb = tf_all + b * S_LEN;

    f16x8 qfrag = *(const f16x8*)(Qbh + (size_t)(i0 + c) * DH + (g << 3));
    const float ti = tb[i0 + c];

    const int kr = ltid >> 2, kc = (ltid & 3) << 3;
    const int vr = ltid >> 3, vc = (ltid & 7) << 3;

    float m2 = -3.0e38f, l = 0.0f;       // l per-lane partial, reduced once
    f32x4 acc0 = {0.f, 0.f, 0.f, 0.f};
    f32x4 acc1 = {0.f, 0.f, 0.f, 0.f};
    const f32x4 zero = {0.f, 0.f, 0.f, 0.f};

    for (int kt = 0; kt < KHALF; kt += 64) {
        __syncthreads();
        *(f16x8*)&Kl[wg][kr][kc] = *(const f16x8*)(Kbh + (size_t)(jbase + kt + kr) * DH + kc);
        *(f16x8*)&Vl[wg][vr][vc] = *(const f16x8*)(Vbh + (size_t)vr * S_LEN + jbase + kt + vc);
        __syncthreads();
        #pragma unroll
        for (int jj = 0; jj < 64; jj += 32) {
            const int j0 = jbase + kt + jj;
            f16x8 kf0 = *(const f16x8*)&Kl[wg][jj + c][g << 3];
            f16x8 kf1 = *(const f16x8*)&Kl[wg][jj + 16 + c][g << 3];
            f32x4 dA = __builtin_amdgcn_mfma_f32_16x16x32_f16(kf0, qfrag, zero, 0, 0, 0);
            f32x4 dB = __builtin_amdgcn_mfma_f32_16x16x32_f16(kf1, qfrag, zero, 0, 0, 0);
            float4 tjA = *(const float4*)(tb + j0 + (g << 2));
            float4 tjB = *(const float4*)(tb + j0 + 16 + (g << 2));
            float eA0 = ti - tjA.x, eA1 = ti - tjA.y, eA2 = ti - tjA.z, eA3 = ti - tjA.w;
            float eB0 = ti - tjB.x, eB1 = ti - tjB.y, eB2 = ti - tjB.z, eB3 = ti - tjB.w;
            float sA0 = (eA0 >= 0.f) ? dA[0] * sc2 - ah2 * eA0 : -1e9f;
            float sA1 = (eA1 >= 0.f) ? dA[1] * sc2 - ah2 * eA1 : -1e9f;
            float sA2 = (eA2 >= 0.f) ? dA[2] * sc2 - ah2 * eA2 : -1e9f;
            float sA3 = (eA3 >= 0.f) ? dA[3] * sc2 - ah2 * eA3 : -1e9f;
            float sB0 = (eB0 >= 0.f) ? dB[0] * sc2 - ah2 * eB0 : -1e9f;
            float sB1 = (eB1 >= 0.f) ? dB[1] * sc2 - ah2 * eB1 : -1e9f;
            float sB2 = (eB2 >= 0.f) ? dB[2] * sc2 - ah2 * eB2 : -1e9f;
            float sB3 = (eB3 >= 0.f) ? dB[3] * sc2 - ah2 * eB3 : -1e9f;
            float pmaxl = fmaxf(fmaxf(fmaxf(sA0, sA1), fmaxf(sA2, sA3)),
                                fmaxf(fmaxf(sB0, sB1), fmaxf(sB2, sB3)));
            if (__any(pmaxl > m2 + 8.0f)) {
                float pm = fmaxf(pmaxl, __shfl_xor(pmaxl, 16, 64));
                pm = fmaxf(pm, __shfl_xor(pm, 32, 64));
                float mnew = fmaxf(m2, pm);
                float fsc = __builtin_amdgcn_exp2f(m2 - mnew);
                m2 = mnew;
                l *= fsc; acc0 *= fsc; acc1 *= fsc;
            }
            float pA0 = __builtin_amdgcn_exp2f(sA0 - m2);
            float pA1 = __builtin_amdgcn_exp2f(sA1 - m2);
            float pA2 = __builtin_amdgcn_exp2f(sA2 - m2);
            float pA3 = __builtin_amdgcn_exp2f(sA3 - m2);
            float pB0 = __builtin_amdgcn_exp2f(sB0 - m2);
            float pB1 = __builtin_amdgcn_exp2f(sB1 - m2);
            float pB2 = __builtin_amdgcn_exp2f(sB2 - m2);
            float pB3 = __builtin_amdgcn_exp2f(sB3 - m2);
            l += ((pA0 + pA1) + (pA2 + pA3)) + ((pB0 + pB1) + (pB2 + pB3));
            f16x4 pfA = {(_Float16)pA0, (_Float16)pA1, (_Float16)pA2, (_Float16)pA3};
            f16x4 pfB = {(_Float16)pB0, (_Float16)pB1, (_Float16)pB2, (_Float16)pB3};
            f16x4 vA0 = *(const f16x4*)&Vl[wg][c][jj + (g << 2)];
            f16x4 vA1 = *(const f16x4*)&Vl[wg][16 + c][jj + (g << 2)];
            f16x4 vB0 = *(const f16x4*)&Vl[wg][c][jj + 16 + (g << 2)];
            f16x4 vB1 = *(const f16x4*)&Vl[wg][16 + c][jj + 16 + (g << 2)];
            acc0 = __builtin_amdgcn_mfma_f32_16x16x16f16(vA0, pfA, acc0, 0, 0, 0);
            acc0 = __builtin_amdgcn_mfma_f32_16x16x16f16(vB0, pfB, acc0, 0, 0, 0);
            acc1 = __builtin_amdgcn_mfma_f32_16x16x16f16(vA1, pfA, acc1, 0, 0, 0);
            acc1 = __builtin_amdgcn_mfma_f32_16x16x16f16(vB1, pfB, acc1, 0, 0, 0);
        }
    }

    l += __shfl_xor(l, 16, 64);
    l += __shfl_xor(l, 32, 64);

    // all waves done reading K/V LDS -> safe to alias as merge scratch
    __syncthreads();
    *(f32x4*)&sacc[w8][c][g << 2] = acc0;
    *(f32x4*)&sacc[w8][c][16 + (g << 2)] = acc1;
    if (g == 0) { sml[w8][0][c] = m2; sml[w8][1][c] = l; }
    __syncthreads();

    // 2-way merge: thread t -> qtile tq, query q, dh block dh0 (4 elems)
    {
        const int tq = tid >> 7;
        const int q = (tid >> 3) & 15;
        const int dh0 = (tid & 7) << 2;
        float m0 = sml[tq][0][q], m1 = sml[tq + 4][0][q];
        float M = fmaxf(m0, m1);
        float f0 = __builtin_amdgcn_exp2f(m0 - M);
        float f1 = __builtin_amdgcn_exp2f(m1 - M);
        float L = sml[tq][1][q] * f0 + sml[tq + 4][1][q] * f1;
        float a0 = sacc[tq][q][dh0 + 0] * f0 + sacc[tq + 4][q][dh0 + 0] * f1;
        float a1 = sacc[tq][q][dh0 + 1] * f0 + sacc[tq + 4][q][dh0 + 1] * f1;
        float a2 = sacc[tq][q][dh0 + 2] * f0 + sacc[tq + 4][q][dh0 + 2] * f1;
        float a3 = sacc[tq][q][dh0 + 3] * f0 + sacc[tq + 4][q][dh0 + 3] * f1;
        if (M < -4.9e8f) {
            // fully-masked row: reference = uniform softmax over ALL 2048 keys.
            float vs0 = 0.f, vs1 = 0.f, vs2 = 0.f, vs3 = 0.f;
            const _Float16* vp = Vbh + (size_t)dh0 * S_LEN + CTX;
            for (int j = 0; j < QQ; j += 8) {
                f16x8 x0 = *(const f16x8*)(vp + j);
                f16x8 x1 = *(const f16x8*)(vp + S_LEN + j);
                f16x8 x2 = *(const f16x8*)(vp + 2 * S_LEN + j);
                f16x8 x3 = *(const f16x8*)(vp + 3 * S_LEN + j);
                #pragma unroll
                for (int e = 0; e < 8; e++) {
                    vs0 += (float)x0[e]; vs1 += (float)x1[e];
                    vs2 += (float)x2[e]; vs3 += (float)x3[e];
                }
            }
            a0 += vs0; a1 += vs1; a2 += vs2; a3 += vs3;
            L += (float)QQ;
        }
        float inv = 1.0f / L;
        int row = b * S_LEN + (itile << 6) + (tq << 4) + q;
        f16x4 o = {(_Float16)(a0 * inv), (_Float16)(a1 * inv),
                   (_Float16)(a2 * inv), (_Float16)(a3 * inv)};
        *(f16x4*)(O + (size_t)row * DD + h * DH + dh0) = o;
    }
}

// ---------------- Output head ----------------
__global__ __launch_bounds__(256) void outhead_k(
    const float* __restrict__ Z, const float* __restrict__ Wout,
    const float* __restrict__ bout, float* __restrict__ out)
{
    int tid = threadIdx.x;
    int rloc = tid >> 4, ho = tid & 15;
    int qrow = blockIdx.x * 16 + rloc;
    int b = qrow >> 9, qi = qrow & (QQ - 1);
    if (ho < HOUTD) {
        const float* z = Z + (size_t)(b * S_LEN + CTX + qi) * DD;
        const float* wr = Wout + (size_t)ho * DD;
        float s = 0.0f;
        for (int d = 0; d < DD; d += 4) {
            float4 zv = *(const float4*)(z + d);
            float4 wv = *(const float4*)(wr + d);
            s += zv.x * wv.x + zv.y * wv.y + zv.z * wv.z + zv.w * wv.w;
        }
        out[(size_t)(b * QQ + qi) * HOUTD + ho] = s + bout[ho];
    }
}

extern "C" void kernel_launch(void* const* d_in, const int* in_sizes, int n_in,
                              void* d_out, int out_size, void* d_ws, size_t ws_size,
                              hipStream_t stream) {
    (void)in_sizes; (void)n_in; (void)out_size; (void)ws_size;
    const float* ctx_x = (const float*)d_in[0];
    const float* ctx_z = (const float*)d_in[1];
    const float* qry_x = (const float*)d_in[2];
    const int* t_ctx = (const int*)d_in[3];
    const int* t_qry = (const int*)d_in[4];
    const float* W_ctx = (const float*)d_in[5];
    const float* b_ctx = (const float*)d_in[6];
    const float* W_qry = (const float*)d_in[7];
    const float* b_qry = (const float*)d_in[8];
    const float* alpha = (const float*)d_in[9];
    const float* Wqkv = (const float*)d_in[10];
    const float* bqkv = (const float*)d_in[11];
    const float* Wo = (const float*)d_in[12];
    const float* bo = (const float*)d_in[13];
    const float* ln1_s = (const float*)d_in[14];
    const float* ln1_b = (const float*)d_in[15];
    const float* W1 = (const float*)d_in[16];
    const float* b1 = (const float*)d_in[17];
    const float* W2 = (const float*)d_in[18];
    const float* b2 = (const float*)d_in[19];
    const float* ln2_s = (const float*)d_in[20];
    const float* ln2_b = (const float*)d_in[21];
    const float* W_out = (const float*)d_in[22];
    const float* b_out = (const float*)d_in[23];

    float* ws = (float*)d_ws;
    const size_t MTOT = (size_t)BB * S_LEN;       // 4096
    const size_t ZSZ = MTOT * DD;                 // 1M floats
    float* Z   = ws;                              // [0, 1M) f32
    float* Yb  = ws + ZSZ;                        // [1M, 2M) f32
    _Float16* Zh   = (_Float16*)(ws + 2 * ZSZ);          // 1M halfs
    _Float16* AYh  = (_Float16*)(ws + 2 * ZSZ + ZSZ / 2);
    _Float16* FF1h = (_Float16*)(ws + 3 * ZSZ);          // 4M halfs -> [3M,5M)
    _Float16* Qh   = (_Float16*)(ws + 5 * ZSZ);
    _Float16* Kh   = (_Float16*)(ws + 5 * ZSZ + ZSZ / 2);
    _Float16* Vh   = (_Float16*)(ws + 6 * ZSZ);
    float* tf_all  = ws + 6 * ZSZ + ZSZ / 2;             // 4096 floats
    _Float16* Whqkv = (_Float16*)(ws + 6 * ZSZ + ZSZ / 2 + 4096);
    _Float16* Who   = Whqkv + (size_t)NL * 3 * DD * DD;
    _Float16* Wh1   = Who   + (size_t)NL * DD * DD;
    _Float16* Wh2   = Wh1   + (size_t)NL * DFF * DD;

    {
        int n4tot = N4_QKV + N4_WO + N4_W1 + N4_W2;
        cvtall_k<<<(n4tot + 255) / 256, 256, 0, stream>>>(
            Wqkv, Wo, W1, W2, Whqkv, Who, Wh1, Wh2);
    }

    embed_k<<<MTOT, 256, 0, stream>>>(ctx_x, ctx_z, qry_x, W_ctx, b_ctx, W_qry, b_qry,
                                      t_ctx, t_qry, Z, Zh, tf_all);

    for (int l = 0; l < NL; l++) {
        hgemm_k<<<dim3(MTOT / 64, (3 * DD) / 64), 256, 0, stream>>>(
            Zh, Whqkv + (size_t)l * 3 * DD * DD, bqkv + (size_t)l * 3 * DD,
            nullptr, nullptr, (int)MTOT, 3 * DD, DD, 2, Qh, Kh, Vh);
        attn_k<<<BB * NH * (S_LEN / 64), 512, 0, stream>>>(
            Qh, Kh, Vh, tf_all, alpha, AYh);
        gemmln_k<<<MTOT / 16, 256, 0, stream>>>(
            AYh, Who + (size_t)l * DD * DD, bo + (size_t)l * DD,
            Z, Zh, ln1_s + (size_t)l * DD, ln1_b + (size_t)l * DD);
        hgemm_k<<<dim3(MTOT / 64, DFF / 64), 256, 0, stream>>>(
            Zh, Wh1 + (size_t)l * DFF * DD, b1 + (size_t)l * DFF,
            nullptr, FF1h, (int)MTOT, DFF, DD, 1, nullptr, nullptr, nullptr);
        hgemm_k<<<dim3(MTOT / 64, DD / 64), 256, 0, stream>>>(
            FF1h, Wh2 + (size_t)l * DD * DFF, b2 + (size_t)l * DD,
            Yb, nullptr, (int)MTOT, DD, DFF, 0, nullptr, nullptr, nullptr);
        ln4_k<<<MTOT / 4, 256, 0, stream>>>(
            Z, Yb, ln2_s + (size_t)l * DD, ln2_b + (size_t)l * DD, Zh);
    }

    outhead_k<<<(BB * QQ) / 16, 256, 0, stream>>>(Z, W_out, b_out, (float*)d_out);
}

// Round 14
// 455.121 us; speedup vs baseline: 1.1416x; 1.0385x over previous
//
#include <hip/hip_runtime.h>
#include <hip/hip_bf16.h>
#include <cstddef>

#define BB   2
#define CTX  1536
#define QQ   512
#define S_LEN 2048
#define DD   256
#define NH   8
#define DH   32
#define DFF  1024
#define NL   6
#define LIN  20
#define HOUTD 10
#define KHALF (CTX / 2)      // 768 keys per wave-group

typedef _Float16 f16x2 __attribute__((ext_vector_type(2)));
typedef _Float16 f16x4 __attribute__((ext_vector_type(4)));
typedef _Float16 f16x8 __attribute__((ext_vector_type(8)));
typedef float f32x4 __attribute__((ext_vector_type(4)));

#define N4_QKV (NL * 3 * DD * DD / 4)
#define N4_WO  (NL * DD * DD / 4)
#define N4_W1  (NL * DFF * DD / 4)
#define N4_W2  (NL * DD * DFF / 4)

// ---------------- fp32 -> f16 convert (all weights, one launch) ----------------
__global__ __launch_bounds__(256) void cvtall_k(
    const float* __restrict__ wqkv, const float* __restrict__ wo,
    const float* __restrict__ w1, const float* __restrict__ w2,
    _Float16* __restrict__ hqkv, _Float16* __restrict__ ho,
    _Float16* __restrict__ h1, _Float16* __restrict__ h2)
{
    int i = blockIdx.x * 256 + threadIdx.x;
    const float* s; _Float16* t; int j = i;
    if (j < N4_QKV) { s = wqkv; t = hqkv; }
    else if ((j -= N4_QKV) < N4_WO) { s = wo; t = ho; }
    else if ((j -= N4_WO) < N4_W1) { s = w1; t = h1; }
    else if ((j -= N4_W1) < N4_W2) { s = w2; t = h2; }
    else return;
    float4 v = ((const float4*)s)[j];
    f16x4 h = {(_Float16)v.x, (_Float16)v.y, (_Float16)v.z, (_Float16)v.w};
    ((f16x4*)t)[j] = h;
}

// ---------------- Embed: Z[b*S+s][d] (+f16 copy, +t_all float) ----------------
__global__ __launch_bounds__(256) void embed_k(
    const float* __restrict__ ctx_x, const float* __restrict__ ctx_z,
    const float* __restrict__ qry_x,
    const float* __restrict__ W_ctx, const float* __restrict__ b_ctx,
    const float* __restrict__ W_qry, const float* __restrict__ b_qry,
    const int* __restrict__ t_ctx, const int* __restrict__ t_qry,
    float* __restrict__ Z, _Float16* __restrict__ Zh, float* __restrict__ tf)
{
    int row = blockIdx.x;            // 0..4095
    int d = threadIdx.x;             // 0..255
    int b = row >> 11, s = row & (S_LEN - 1);
    float acc;
    if (s < CTX) {
        const float* x1 = ctx_x + (size_t)(b * CTX + s) * LIN;
        const float* x2 = ctx_z + (size_t)(b * CTX + s) * HOUTD;
        const float* w = W_ctx + (size_t)d * (LIN + HOUTD);
        acc = b_ctx[d];
        #pragma unroll
        for (int i = 0; i < LIN; i++) acc += x1[i] * w[i];
        #pragma unroll
        for (int i = 0; i < HOUTD; i++) acc += x2[i] * w[LIN + i];
        if (d == 0) tf[row] = (float)t_ctx[b * CTX + s];
    } else {
        int qi = s - CTX;
        const float* x1 = qry_x + (size_t)(b * QQ + qi) * LIN;
        const float* w = W_qry + (size_t)d * (LIN + HOUTD);
        acc = b_qry[d];
        #pragma unroll
        for (int i = 0; i < LIN; i++) acc += x1[i] * w[i];
        if (d == 0) tf[row] = (float)t_qry[b * QQ + qi];
    }
    Z[(size_t)row * DD + d] = acc;
    Zh[(size_t)row * DD + d] = (_Float16)acc;
}

// ---------------- MFMA f16 GEMM (dbuf LDS, pad-40, 1 barrier/step) ----------------
// mode 0: fp32 out Y   mode 1: relu -> f16 Yh   mode 2: f16 Q,K:[B,NH,S,DH] V:[B,NH,DH,S]
__global__ __launch_bounds__(256) void hgemm_k(
    const _Float16* __restrict__ X, const _Float16* __restrict__ W,
    const float* __restrict__ bias, float* __restrict__ Y,
    _Float16* __restrict__ Yh, int M, int N, int K, int mode,
    _Float16* __restrict__ Qh, _Float16* __restrict__ Kh, _Float16* __restrict__ Vh)
{
    __shared__ _Float16 Ah[2][64][40];
    __shared__ _Float16 Bh[2][64][40];
    const int tid = threadIdx.x;
    const int bm = blockIdx.x << 6, bn = blockIdx.y << 6;
    const int lr = tid >> 2;
    const int lk = (tid & 3) << 3;
    const int w = tid >> 6, lane = tid & 63;
    const int c = lane & 15, g = lane >> 4;
    const int wm = (w >> 1) << 5, wn = (w & 1) << 5;

    f32x4 acc00 = {0.f,0.f,0.f,0.f}, acc01 = {0.f,0.f,0.f,0.f};
    f32x4 acc10 = {0.f,0.f,0.f,0.f}, acc11 = {0.f,0.f,0.f,0.f};

    const _Float16* Xp = X + (size_t)(bm + lr) * K + lk;
    const _Float16* Wp = W + (size_t)(bn + lr) * K + lk;

    f16x8 xa = *(const f16x8*)Xp;
    f16x8 wb = *(const f16x8*)Wp;
    const int nt = K >> 5;
    int buf = 0;
    for (int t = 0; t < nt; t++) {
        *(f16x8*)&Ah[buf][lr][lk] = xa;
        *(f16x8*)&Bh[buf][lr][lk] = wb;
        __syncthreads();
        if (t + 1 < nt) {
            xa = *(const f16x8*)(Xp + ((size_t)(t + 1) << 5));
            wb = *(const f16x8*)(Wp + ((size_t)(t + 1) << 5));
        }
        f16x8 a0 = *(const f16x8*)&Ah[buf][wm + c][g << 3];
        f16x8 a1 = *(const f16x8*)&Ah[buf][wm + 16 + c][g << 3];
        f16x8 b0 = *(const f16x8*)&Bh[buf][wn + c][g << 3];
        f16x8 b1 = *(const f16x8*)&Bh[buf][wn + 16 + c][g << 3];
        acc00 = __builtin_amdgcn_mfma_f32_16x16x32_f16(a0, b0, acc00, 0, 0, 0);
        acc01 = __builtin_amdgcn_mfma_f32_16x16x32_f16(a0, b1, acc01, 0, 0, 0);
        acc10 = __builtin_amdgcn_mfma_f32_16x16x32_f16(a1, b0, acc10, 0, 0, 0);
        acc11 = __builtin_amdgcn_mfma_f32_16x16x32_f16(a1, b1, acc11, 0, 0, 0);
        buf ^= 1;
    }

    f32x4 accs[2][2] = {{acc00, acc01}, {acc10, acc11}};
    #pragma unroll
    for (int fm = 0; fm < 2; fm++) {
        #pragma unroll
        for (int fn = 0; fn < 2; fn++) {
            int colb = bn + wn + (fn << 4) + c;
            float bv = bias[colb];
            #pragma unroll
            for (int r = 0; r < 4; r++) {
                int row = bm + wm + (fm << 4) + (g << 2) + r;
                float v = accs[fm][fn][r] + bv;
                if (mode == 0) {
                    Y[(size_t)row * N + colb] = v;
                } else if (mode == 1) {
                    Yh[(size_t)row * N + colb] = (_Float16)fmaxf(v, 0.0f);
                } else {
                    int which = colb >> 8, h = (colb >> 5) & 7, d = colb & 31;
                    int bb2 = row >> 11, ss = row & (S_LEN - 1);
                    int bhi = (bb2 << 3) + h;
                    _Float16 hv = (_Float16)v;
                    if (which == 0)      Qh[((size_t)bhi * S_LEN + ss) * DH + d] = hv;
                    else if (which == 1) Kh[((size_t)bhi * S_LEN + ss) * DH + d] = hv;
                    else                 Vh[((size_t)bhi * DH + d) * S_LEN + ss] = hv;
                }
            }
        }
    }
}

// ---------------- fused Wo GEMM + residual + LayerNorm (BM=16, grid 256) ----------------
__global__ __launch_bounds__(256) void gemmln_k(
    const _Float16* __restrict__ X, const _Float16* __restrict__ W,
    const float* __restrict__ bias, float* __restrict__ Z,
    _Float16* __restrict__ Zh, const float* __restrict__ sw,
    const float* __restrict__ bw)
{
    __shared__ _Float16 Ast[2][16][40];
    __shared__ _Float16 Bst[2][256][40];
    __shared__ float lred[4][16][2];
    const int tid = threadIdx.x;
    const int bm = blockIdx.x << 4;
    const int w = tid >> 6, lane = tid & 63;
    const int c = lane & 15, g = lane >> 4;
    const int br = tid >> 2, bk = (tid & 3) << 3;

    f32x4 acc[4] = {};
    const _Float16* Wp = W + (size_t)br * DD + bk;
    f16x8 p0 = *(const f16x8*)Wp;
    f16x8 p1 = *(const f16x8*)(Wp + (size_t)64 * DD);
    f16x8 p2 = *(const f16x8*)(Wp + (size_t)128 * DD);
    f16x8 p3 = *(const f16x8*)(Wp + (size_t)192 * DD);
    f16x8 xa;
    if (tid < 64) xa = *(const f16x8*)(X + (size_t)(bm + br) * DD + bk);
    int buf = 0;
    #pragma unroll
    for (int t = 0; t < 8; t++) {
        if (tid < 64) *(f16x8*)&Ast[buf][br][bk] = xa;
        *(f16x8*)&Bst[buf][br][bk] = p0;
        *(f16x8*)&Bst[buf][br + 64][bk] = p1;
        *(f16x8*)&Bst[buf][br + 128][bk] = p2;
        *(f16x8*)&Bst[buf][br + 192][bk] = p3;
        __syncthreads();
        if (t < 7) {
            int o = (t + 1) << 5;
            if (tid < 64) xa = *(const f16x8*)(X + (size_t)(bm + br) * DD + o + bk);
            p0 = *(const f16x8*)(Wp + o);
            p1 = *(const f16x8*)(Wp + (size_t)64 * DD + o);
            p2 = *(const f16x8*)(Wp + (size_t)128 * DD + o);
            p3 = *(const f16x8*)(Wp + (size_t)192 * DD + o);
        }
        f16x8 a = *(const f16x8*)&Ast[buf][c][g << 3];
        #pragma unroll
        for (int f = 0; f < 4; f++) {
            f16x8 bfr = *(const f16x8*)&Bst[buf][(w << 6) + (f << 4) + c][g << 3];
            acc[f] = __builtin_amdgcn_mfma_f32_16x16x32_f16(a, bfr, acc[f], 0, 0, 0);
        }
        buf ^= 1;
    }

    float vals[4][4];
    float s1[4] = {0.f,0.f,0.f,0.f}, s2[4] = {0.f,0.f,0.f,0.f};
    #pragma unroll
    for (int f = 0; f < 4; f++) {
        int col = (w << 6) + (f << 4) + c;
        float bv = bias[col];
        #pragma unroll
        for (int r = 0; r < 4; r++) {
            int row = bm + (g << 2) + r;
            float v = acc[f][r] + bv + Z[(size_t)row * DD + col];
            vals[f][r] = v; s1[r] += v; s2[r] += v * v;
        }
    }
    #pragma unroll
    for (int off = 1; off < 16; off <<= 1) {
        #pragma unroll
        for (int r = 0; r < 4; r++) {
            s1[r] += __shfl_xor(s1[r], off, 64);
            s2[r] += __shfl_xor(s2[r], off, 64);
        }
    }
    if (c == 0) {
        #pragma unroll
        for (int r = 0; r < 4; r++) {
            lred[w][(g << 2) + r][0] = s1[r];
            lred[w][(g << 2) + r][1] = s2[r];
        }
    }
    __syncthreads();
    float mu_r[4], rs_r[4];
    #pragma unroll
    for (int r = 0; r < 4; r++) {
        int lr_ = (g << 2) + r;
        float S1 = lred[0][lr_][0] + lred[1][lr_][0] + lred[2][lr_][0] + lred[3][lr_][0];
        float S2 = lred[0][lr_][1] + lred[1][lr_][1] + lred[2][lr_][1] + lred[3][lr_][1];
        float mu = S1 * (1.0f / 256.0f);
        float var = S2 * (1.0f / 256.0f) - mu * mu;
        mu_r[r] = mu; rs_r[r] = rsqrtf(var + 1e-5f);
    }
    #pragma unroll
    for (int f = 0; f < 4; f++) {
        int col = (w << 6) + (f << 4) + c;
        float swv = sw[col], bwv = bw[col];
        #pragma unroll
        for (int r = 0; r < 4; r++) {
            int row = bm + (g << 2) + r;
            float o = (vals[f][r] - mu_r[r]) * rs_r[r] * swv + bwv;
            Z[(size_t)row * DD + col] = o;
            Zh[(size_t)row * DD + col] = (_Float16)o;
        }
    }
}

// ---------------- Residual + LN, one WAVE per row (no LDS, no barrier) ----------------
__global__ __launch_bounds__(256) void ln4_k(
    float* __restrict__ Z, const float* __restrict__ Y,
    const float* __restrict__ sw, const float* __restrict__ bw,
    _Float16* __restrict__ Zh)
{
    const int w = threadIdx.x >> 6, lane = threadIdx.x & 63;
    const int row = (blockIdx.x << 2) + w;
    float4 z = ((const float4*)(Z + (size_t)row * DD))[lane];
    float4 y = ((const float4*)(Y + (size_t)row * DD))[lane];
    float x0 = z.x + y.x, x1 = z.y + y.y, x2 = z.z + y.z, x3 = z.w + y.w;
    float s1 = (x0 + x1) + (x2 + x3);
    float s2 = (x0 * x0 + x1 * x1) + (x2 * x2 + x3 * x3);
    #pragma unroll
    for (int off = 1; off < 64; off <<= 1) {
        s1 += __shfl_xor(s1, off, 64);
        s2 += __shfl_xor(s2, off, 64);
    }
    float mu = s1 * (1.0f / 256.0f);
    float var = s2 * (1.0f / 256.0f) - mu * mu;
    float rs = rsqrtf(var + 1e-5f);
    float4 sv = ((const float4*)sw)[lane];
    float4 bv = ((const float4*)bw)[lane];
    float o0 = (x0 - mu) * rs * sv.x + bv.x;
    float o1 = (x1 - mu) * rs * sv.y + bv.y;
    float o2 = (x2 - mu) * rs * sv.z + bv.z;
    float o3 = (x3 - mu) * rs * sv.w + bv.w;
    ((float4*)(Z + (size_t)row * DD))[lane] = make_float4(o0, o1, o2, o3);
    f16x4 oh = {(_Float16)o0, (_Float16)o1, (_Float16)o2, (_Float16)o3};
    ((f16x4*)(Zh + (size_t)row * DD))[lane] = oh;
}

// ---------------- MFMA flash attention ----------------
// 1024 thr = 16 waves = 2 key-split wg x 8 query tiles (128 queries/block).
// Grid 256 -> 1 block/CU x 16 waves. K/V staged ONCE per 128 queries (2x
// less L1 staging than 64-q blocks); dbuf; staging split K-waves/V-waves.
// Merge scratch aliases K/V LDS. launch_bounds(1024,4) -> 128 VGPR, no spill.
__global__ __launch_bounds__(1024, 4) void attn_k(
    const _Float16* __restrict__ Qf, const _Float16* __restrict__ Kf,
    const _Float16* __restrict__ Vf, const float* __restrict__ tf_all,
    const float* __restrict__ alpha, _Float16* __restrict__ O)
{
    const int bh = blockIdx.x >> 4;           // /(S/128)=16
    const int itile = blockIdx.x & 15;
    const int b = bh >> 3, h = bh & 7;
    const int tid = threadIdx.x;
    const int w16 = tid >> 6;                 // 0..15
    const int wg = w16 >> 3;                  // key-split 0/1
    const int wq = w16 & 7;                   // query tile 0..7
    const int ltid = tid & 511;               // within wave-group
    const int lane = tid & 63;
    const int c = lane & 15, g = lane >> 4;
    const int i0 = (itile << 7) + (wq << 4);
    const int jbase = wg * KHALF;

    // K: [2][2][64][40] = 20480 B ; V: [2][2][32][72] = 18432 B ; total 38912.
    // Merge aliases: sacc[16][16][36] f32 = 36864 B ; sml[16][2][16] = 2048 B.
    __shared__ __align__(16) char smem[38912];
    _Float16 (*Kl)[2][64][40] = (_Float16(*)[2][64][40])smem;
    _Float16 (*Vl)[2][32][72] = (_Float16(*)[2][32][72])(smem + 20480);
    float (*sacc)[16][36] = (float(*)[16][36])smem;
    float (*sml)[2][16] = (float(*)[2][16])(smem + 36864);

    const float LOG2E = 1.44269504088896f;
    const float sc2 = 0.17677669529663687f * LOG2E;
    const float ah2 = alpha[h] * LOG2E;

    const _Float16* Qbh = Qf + (size_t)bh * S_LEN * DH;
    const _Float16* Kbh = Kf + (size_t)bh * S_LEN * DH;
    const _Float16* Vbh = Vf + (size_t)bh * DH * S_LEN;
    const float* tb = tf_all + b * S_LEN;

    f16x8 qfrag = *(const f16x8*)(Qbh + (size_t)(i0 + c) * DH + (g << 3));
    const float ti = tb[i0 + c];

    // staging: first 256 threads of wg stage K (64x32), next 256 stage V (32x64)
    const int lh = ltid & 255;
    const int kr = lh >> 2, kc = (lh & 3) << 3;
    const int vr = lh >> 3, vc = (lh & 7) << 3;
    const bool doK = (ltid < 256);

    float m2 = -3.0e38f, l = 0.0f;       // l per-lane partial, reduced once
    f32x4 acc0 = {0.f, 0.f, 0.f, 0.f};
    f32x4 acc1 = {0.f, 0.f, 0.f, 0.f};
    const f32x4 zero = {0.f, 0.f, 0.f, 0.f};

    f16x8 pre;
    if (doK) pre = *(const f16x8*)(Kbh + (size_t)(jbase + kr) * DH + kc);
    else     pre = *(const f16x8*)(Vbh + (size_t)vr * S_LEN + jbase + vc);
    int buf = 0;

    for (int kt = 0; kt < KHALF; kt += 64) {
        if (doK) *(f16x8*)&Kl[wg][buf][kr][kc] = pre;
        else     *(f16x8*)&Vl[wg][buf][vr][vc] = pre;
        __syncthreads();
        if (kt + 64 < KHALF) {
            if (doK) pre = *(const f16x8*)(Kbh + (size_t)(jbase + kt + 64 + kr) * DH + kc);
            else     pre = *(const f16x8*)(Vbh + (size_t)vr * S_LEN + jbase + kt + 64 + vc);
        }
        #pragma unroll
        for (int jj = 0; jj < 64; jj += 32) {
            const int j0 = jbase + kt + jj;
            f16x8 kf0 = *(const f16x8*)&Kl[wg][buf][jj + c][g << 3];
            f16x8 kf1 = *(const f16x8*)&Kl[wg][buf][jj + 16 + c][g << 3];
            f32x4 dA = __builtin_amdgcn_mfma_f32_16x16x32_f16(kf0, qfrag, zero, 0, 0, 0);
            f32x4 dB = __builtin_amdgcn_mfma_f32_16x16x32_f16(kf1, qfrag, zero, 0, 0, 0);
            float4 tjA = *(const float4*)(tb + j0 + (g << 2));
            float4 tjB = *(const float4*)(tb + j0 + 16 + (g << 2));
            float eA0 = ti - tjA.x, eA1 = ti - tjA.y, eA2 = ti - tjA.z, eA3 = ti - tjA.w;
            float eB0 = ti - tjB.x, eB1 = ti - tjB.y, eB2 = ti - tjB.z, eB3 = ti - tjB.w;
            float sA0 = (eA0 >= 0.f) ? dA[0] * sc2 - ah2 * eA0 : -1e9f;
            float sA1 = (eA1 >= 0.f) ? dA[1] * sc2 - ah2 * eA1 : -1e9f;
            float sA2 = (eA2 >= 0.f) ? dA[2] * sc2 - ah2 * eA2 : -1e9f;
            float sA3 = (eA3 >= 0.f) ? dA[3] * sc2 - ah2 * eA3 : -1e9f;
            float sB0 = (eB0 >= 0.f) ? dB[0] * sc2 - ah2 * eB0 : -1e9f;
            float sB1 = (eB1 >= 0.f) ? dB[1] * sc2 - ah2 * eB1 : -1e9f;
            float sB2 = (eB2 >= 0.f) ? dB[2] * sc2 - ah2 * eB2 : -1e9f;
            float sB3 = (eB3 >= 0.f) ? dB[3] * sc2 - ah2 * eB3 : -1e9f;
            float pmaxl = fmaxf(fmaxf(fmaxf(sA0, sA1), fmaxf(sA2, sA3)),
                                fmaxf(fmaxf(sB0, sB1), fmaxf(sB2, sB3)));
            if (__any(pmaxl > m2 + 8.0f)) {
                float pm = fmaxf(pmaxl, __shfl_xor(pmaxl, 16, 64));
                pm = fmaxf(pm, __shfl_xor(pm, 32, 64));
                float mnew = fmaxf(m2, pm);
                float fsc = __builtin_amdgcn_exp2f(m2 - mnew);
                m2 = mnew;
                l *= fsc; acc0 *= fsc; acc1 *= fsc;
            }
            float pA0 = __builtin_amdgcn_exp2f(sA0 - m2);
            float pA1 = __builtin_amdgcn_exp2f(sA1 - m2);
            float pA2 = __builtin_amdgcn_exp2f(sA2 - m2);
            float pA3 = __builtin_amdgcn_exp2f(sA3 - m2);
            float pB0 = __builtin_amdgcn_exp2f(sB0 - m2);
            float pB1 = __builtin_amdgcn_exp2f(sB1 - m2);
            float pB2 = __builtin_amdgcn_exp2f(sB2 - m2);
            float pB3 = __builtin_amdgcn_exp2f(sB3 - m2);
            l += ((pA0 + pA1) + (pA2 + pA3)) + ((pB0 + pB1) + (pB2 + pB3));
            f16x4 pfA = {(_Float16)pA0, (_Float16)pA1, (_Float16)pA2, (_Float16)pA3};
            f16x4 pfB = {(_Float16)pB0, (_Float16)pB1, (_Float16)pB2, (_Float16)pB3};
            f16x4 vA0 = *(const f16x4*)&Vl[wg][buf][c][jj + (g << 2)];
            f16x4 vA1 = *(const f16x4*)&Vl[wg][buf][16 + c][jj + (g << 2)];
            f16x4 vB0 = *(const f16x4*)&Vl[wg][buf][c][jj + 16 + (g << 2)];
            f16x4 vB1 = *(const f16x4*)&Vl[wg][buf][16 + c][jj + 16 + (g << 2)];
            acc0 = __builtin_amdgcn_mfma_f32_16x16x16f16(vA0, pfA, acc0, 0, 0, 0);
            acc0 = __builtin_amdgcn_mfma_f32_16x16x16f16(vB0, pfB, acc0, 0, 0, 0);
            acc1 = __builtin_amdgcn_mfma_f32_16x16x16f16(vA1, pfA, acc1, 0, 0, 0);
            acc1 = __builtin_amdgcn_mfma_f32_16x16x16f16(vB1, pfB, acc1, 0, 0, 0);
        }
        buf ^= 1;
    }

    l += __shfl_xor(l, 16, 64);
    l += __shfl_xor(l, 32, 64);

    // all waves done reading K/V LDS -> safe to alias as merge scratch
    __syncthreads();
    *(f32x4*)&sacc[w16][c][g << 2] = acc0;
    *(f32x4*)&sacc[w16][c][16 + (g << 2)] = acc1;
    if (g == 0) { sml[w16][0][c] = m2; sml[w16][1][c] = l; }
    __syncthreads();

    // 2-way merge: thread t -> qtile qt (0..7), query q, dh block dh0 (4 elems)
    {
        const int qt = tid >> 7;
        const int q = (tid >> 3) & 15;
        const int dh0 = (tid & 7) << 2;
        float m0 = sml[qt][0][q], m1 = sml[qt + 8][0][q];
        float M = fmaxf(m0, m1);
        float f0 = __builtin_amdgcn_exp2f(m0 - M);
        float f1 = __builtin_amdgcn_exp2f(m1 - M);
        float L = sml[qt][1][q] * f0 + sml[qt + 8][1][q] * f1;
        float a0 = sacc[qt][q][dh0 + 0] * f0 + sacc[qt + 8][q][dh0 + 0] * f1;
        float a1 = sacc[qt][q][dh0 + 1] * f0 + sacc[qt + 8][q][dh0 + 1] * f1;
        float a2 = sacc[qt][q][dh0 + 2] * f0 + sacc[qt + 8][q][dh0 + 2] * f1;
        float a3 = sacc[qt][q][dh0 + 3] * f0 + sacc[qt + 8][q][dh0 + 3] * f1;
        if (M < -4.9e8f) {
            // fully-masked row: reference = uniform softmax over ALL 2048 keys.
            float vs0 = 0.f, vs1 = 0.f, vs2 = 0.f, vs3 = 0.f;
            const _Float16* vp = Vbh + (size_t)dh0 * S_LEN + CTX;
            for (int j = 0; j < QQ; j += 8) {
                f16x8 x0 = *(const f16x8*)(vp + j);
                f16x8 x1 = *(const f16x8*)(vp + S_LEN + j);
                f16x8 x2 = *(const f16x8*)(vp + 2 * S_LEN + j);
                f16x8 x3 = *(const f16x8*)(vp + 3 * S_LEN + j);
                #pragma unroll
                for (int e = 0; e < 8; e++) {
                    vs0 += (float)x0[e]; vs1 += (float)x1[e];
                    vs2 += (float)x2[e]; vs3 += (float)x3[e];
                }
            }
            a0 += vs0; a1 += vs1; a2 += vs2; a3 += vs3;
            L += (float)QQ;
        }
        float inv = 1.0f / L;
        int row = b * S_LEN + (itile << 7) + (qt << 4) + q;
        f16x4 o = {(_Float16)(a0 * inv), (_Float16)(a1 * inv),
                   (_Float16)(a2 * inv), (_Float16)(a3 * inv)};
        *(f16x4*)(O + (size_t)row * DD + h * DH + dh0) = o;
    }
}

// ---------------- Output head ----------------
__global__ __launch_bounds__(256) void outhead_k(
    const float* __restrict__ Z, const float* __restrict__ Wout,
    const float* __restrict__ bout, float* __restrict__ out)
{
    int tid = threadIdx.x;
    int rloc = tid >> 4, ho = tid & 15;
    int qrow = blockIdx.x * 16 + rloc;
    int b = qrow >> 9, qi = qrow & (QQ - 1);
    if (ho < HOUTD) {
        const float* z = Z + (size_t)(b * S_LEN + CTX + qi) * DD;
        const float* wr = Wout + (size_t)ho * DD;
        float s = 0.0f;
        for (int d = 0; d < DD; d += 4) {
            float4 zv = *(const float4*)(z + d);
            float4 wv = *(const float4*)(wr + d);
            s += zv.x * wv.x + zv.y * wv.y + zv.z * wv.z + zv.w * wv.w;
        }
        out[(size_t)(b * QQ + qi) * HOUTD + ho] = s + bout[ho];
    }
}

extern "C" void kernel_launch(void* const* d_in, const int* in_sizes, int n_in,
                              void* d_out, int out_size, void* d_ws, size_t ws_size,
                              hipStream_t stream) {
    (void)in_sizes; (void)n_in; (void)out_size; (void)ws_size;
    const float* ctx_x = (const float*)d_in[0];
    const float* ctx_z = (const float*)d_in[1];
    const float* qry_x = (const float*)d_in[2];
    const int* t_ctx = (const int*)d_in[3];
    const int* t_qry = (const int*)d_in[4];
    const float* W_ctx = (const float*)d_in[5];
    const float* b_ctx = (const float*)d_in[6];
    const float* W_qry = (const float*)d_in[7];
    const float* b_qry = (const float*)d_in[8];
    const float* alpha = (const float*)d_in[9];
    const float* Wqkv = (const float*)d_in[10];
    const float* bqkv = (const float*)d_in[11];
    const float* Wo = (const float*)d_in[12];
    const float* bo = (const float*)d_in[13];
    const float* ln1_s = (const float*)d_in[14];
    const float* ln1_b = (const float*)d_in[15];
    const float* W1 = (const float*)d_in[16];
    const float* b1 = (const float*)d_in[17];
    const float* W2 = (const float*)d_in[18];
    const float* b2 = (const float*)d_in[19];
    const float* ln2_s = (const float*)d_in[20];
    const float* ln2_b = (const float*)d_in[21];
    const float* W_out = (const float*)d_in[22];
    const float* b_out = (const float*)d_in[23];

    float* ws = (float*)d_ws;
    const size_t MTOT = (size_t)BB * S_LEN;       // 4096
    const size_t ZSZ = MTOT * DD;                 // 1M floats
    float* Z   = ws;                              // [0, 1M) f32
    float* Yb  = ws + ZSZ;                        // [1M, 2M) f32
    _Float16* Zh   = (_Float16*)(ws + 2 * ZSZ);          // 1M halfs
    _Float16* AYh  = (_Float16*)(ws + 2 * ZSZ + ZSZ / 2);
    _Float16* FF1h = (_Float16*)(ws + 3 * ZSZ);          // 4M halfs -> [3M,5M)
    _Float16* Qh   = (_Float16*)(ws + 5 * ZSZ);
    _Float16* Kh   = (_Float16*)(ws + 5 * ZSZ + ZSZ / 2);
    _Float16* Vh   = (_Float16*)(ws + 6 * ZSZ);
    float* tf_all  = ws + 6 * ZSZ + ZSZ / 2;             // 4096 floats
    _Float16* Whqkv = (_Float16*)(ws + 6 * ZSZ + ZSZ / 2 + 4096);
    _Float16* Who   = Whqkv + (size_t)NL * 3 * DD * DD;
    _Float16* Wh1   = Who   + (size_t)NL * DD * DD;
    _Float16* Wh2   = Wh1   + (size_t)NL * DFF * DD;

    {
        int n4tot = N4_QKV + N4_WO + N4_W1 + N4_W2;
        cvtall_k<<<(n4tot + 255) / 256, 256, 0, stream>>>(
            Wqkv, Wo, W1, W2, Whqkv, Who, Wh1, Wh2);
    }

    embed_k<<<MTOT, 256, 0, stream>>>(ctx_x, ctx_z, qry_x, W_ctx, b_ctx, W_qry, b_qry,
                                      t_ctx, t_qry, Z, Zh, tf_all);

    for (int l = 0; l < NL; l++) {
        hgemm_k<<<dim3(MTOT / 64, (3 * DD) / 64), 256, 0, stream>>>(
            Zh, Whqkv + (size_t)l * 3 * DD * DD, bqkv + (size_t)l * 3 * DD,
            nullptr, nullptr, (int)MTOT, 3 * DD, DD, 2, Qh, Kh, Vh);
        attn_k<<<BB * NH * (S_LEN / 128), 1024, 0, stream>>>(
            Qh, Kh, Vh, tf_all, alpha, AYh);
        gemmln_k<<<MTOT / 16, 256, 0, stream>>>(
            AYh, Who + (size_t)l * DD * DD, bo + (size_t)l * DD,
            Z, Zh, ln1_s + (size_t)l * DD, ln1_b + (size_t)l * DD);
        hgemm_k<<<dim3(MTOT / 64, DFF / 64), 256, 0, stream>>>(
            Zh, Wh1 + (size_t)l * DFF * DD, b1 + (size_t)l * DFF,
            nullptr, FF1h, (int)MTOT, DFF, DD, 1, nullptr, nullptr, nullptr);
        hgemm_k<<<dim3(MTOT / 64, DD / 64), 256, 0, stream>>>(
            FF1h, Wh2 + (size_t)l * DD * DFF, b2 + (size_t)l * DD,
            Yb, nullptr, (int)MTOT, DD, DFF, 0, nullptr, nullptr, nullptr);
        ln4_k<<<MTOT / 4, 256, 0, stream>>>(
            Z, Yb, ln2_s + (size_t)l * DD, ln2_b + (size_t)l * DD, Zh);
    }

    outhead_k<<<(BB * QQ) / 16, 256, 0, stream>>>(Z, W_out, b_out, (float*)d_out);
}